// Round 1
// baseline (68.431 us; speedup 1.0000x reference)
//
#include <hip/hip_runtime.h>

// EMA scan: out[l,b,d,e] = dec[e]*x[l,b,d] + (1-dec[e])*out[l-1,b,d,e],
// init state = x[0,b,d]. dec = sigmoid(log_decay).
//
// R7: exact chunk-carry decomposition replaces halo recompute.
//   Theory: all 1024 blocks are co-resident and start with a 128-step halo
//   (no stores) -> ~20us of HBM-write-idle front, then the 268MB write burst:
//   T ~= T_halo + T_write ~= 67us observed. Carry decomposition removes the
//   halo: kernel A computes per-chunk aggregates h (zero-init 32-step EMA),
//   kernel B scans carries across 128 chunks (16K threads, in-place in ws),
//   kernel C starts storing immediately from the exact carry. Also makes the
//   result exact (absmax ~1e-5 vs 0.021).

#define LL    4096
#define BB    16
#define DD    128
#define EMAS  8
#define BDSZ  (BB * DD)              // 2048
#define CHUNK 32
#define NCHUNK (LL / CHUNK)          // 128
#define SLICE (BDSZ * EMAS)          // 16384 floats per chunk slice in ws
#define WS_BYTES ((size_t)NCHUNK * SLICE * sizeof(float))   // 8 MiB

typedef float f32x4 __attribute__((ext_vector_type(4)));

__device__ __forceinline__ void load_decays(const float* __restrict__ log_decay,
                                            float* dec, float* a) {
#pragma unroll
    for (int e = 0; e < EMAS; ++e) {
        const float ld = log_decay[e];
        const float dd = 1.0f / (1.0f + __expf(-ld));
        dec[e] = dd;
        a[e]   = 1.0f - dd;
    }
}

// ---------------- Kernel A: per-chunk aggregates ----------------
// h_c[e] = sum_{k=0..31} dec[e] * a[e]^(31-k) * x[32c+k]
// (equals a 32-step EMA starting from state 0)
__global__ __launch_bounds__(256) void ema_agg(const float* __restrict__ x,
                                               const float* __restrict__ log_decay,
                                               float* __restrict__ hws) {
    const int tid   = threadIdx.x;
    const int chunk = blockIdx.x >> 3;
    const int off   = ((blockIdx.x & 7) << 8) + tid;   // == b*DD + d

    float dec[EMAS], a[EMAS];
    load_decays(log_decay, dec, a);

    const float* xp = x + (size_t)chunk * CHUNK * BDSZ + off;
    float xv[CHUNK];
#pragma unroll
    for (int k = 0; k < CHUNK; ++k) xv[k] = xp[(size_t)k * BDSZ];

    float s[EMAS];
#pragma unroll
    for (int e = 0; e < EMAS; ++e) s[e] = 0.0f;
#pragma unroll
    for (int k = 0; k < CHUNK; ++k) {
        const float xk = xv[k];
#pragma unroll
        for (int e = 0; e < EMAS; ++e) s[e] = fmaf(a[e], s[e], dec[e] * xk);
    }

    f32x4* hp = (f32x4*)(hws + (size_t)chunk * SLICE + (size_t)off * EMAS);
    f32x4 lo = {s[0], s[1], s[2], s[3]};
    f32x4 hi = {s[4], s[5], s[6], s[7]};
    hp[0] = lo;
    hp[1] = hi;
}

// ---------------- Kernel B: scan carries across chunks ----------------
// carry_0 = x[0,b,d]; carry_{c+1} = a^32 * carry_c + h_c.
// In-place: slot c is read (h_c) then overwritten with carry_c.
// One thread per (b,d,e): 16384 threads, fully coalesced per chunk slice.
__global__ __launch_bounds__(256) void ema_scan(const float* __restrict__ x,
                                                const float* __restrict__ log_decay,
                                                float* __restrict__ hws) {
    const int tid = blockIdx.x * 256 + threadIdx.x;    // 0..16383
    const int e   = tid & (EMAS - 1);
    const int bd  = tid >> 3;

    const float ld  = log_decay[e];
    const float dec = 1.0f / (1.0f + __expf(-ld));
    const float a   = 1.0f - dec;
    float A = a * a;           // a^2
    A = A * A;                 // a^4
    A = A * A;                 // a^8
    A = A * A;                 // a^16
    A = A * A;                 // a^32

    float s = x[bd];           // carry into chunk 0 = x[0,b,d]
    float* hp = hws + tid;

#define PF 16                  // prefetch depth: cover cross-XCD L2/L3 latency
    float buf[PF];
#pragma unroll
    for (int i = 0; i < PF; ++i) buf[i] = hp[(size_t)i * SLICE];

    for (int c0 = 0; c0 < NCHUNK; c0 += PF) {
        float nbuf[PF];
        if (c0 + PF < NCHUNK) {
#pragma unroll
            for (int i = 0; i < PF; ++i) nbuf[i] = hp[(size_t)(c0 + PF + i) * SLICE];
        } else {
#pragma unroll
            for (int i = 0; i < PF; ++i) nbuf[i] = 0.0f;
        }
#pragma unroll
        for (int i = 0; i < PF; ++i) {
            const float hv = buf[i];
            hp[(size_t)(c0 + i) * SLICE] = s;   // publish carry into chunk c0+i
            s = fmaf(A, s, hv);                 // carry into next chunk
        }
#pragma unroll
        for (int i = 0; i < PF; ++i) buf[i] = nbuf[i];
    }
#undef PF
}

// ---------------- Kernel C: exact main pass, no halo ----------------
__global__ __launch_bounds__(256) void ema_main(const float* __restrict__ x,
                                                const float* __restrict__ log_decay,
                                                const float* __restrict__ carry,
                                                float* __restrict__ out) {
    const int tid   = threadIdx.x;
    const int chunk = blockIdx.x >> 3;
    const int off   = ((blockIdx.x & 7) << 8) + tid;

    float dec[EMAS], a[EMAS];
    load_decays(log_decay, dec, a);

    const int cstart = chunk * CHUNK;
    const float* xp  = x + (size_t)cstart * BDSZ + off;

    float xv[CHUNK];
#pragma unroll
    for (int k = 0; k < CHUNK; ++k) xv[k] = xp[(size_t)k * BDSZ];

    const f32x4* cp = (const f32x4*)(carry + (size_t)chunk * SLICE + (size_t)off * EMAS);
    f32x4 clo = cp[0];
    f32x4 chi = cp[1];
    float s[EMAS];
#pragma unroll
    for (int i = 0; i < 4; ++i) { s[i] = clo[i]; s[4 + i] = chi[i]; }

    f32x4* op = (f32x4*)(out + ((size_t)cstart * BDSZ + off) * EMAS);
    const int opstride = SLICE / 4;            // f32x4s per l-step
#pragma unroll
    for (int k = 0; k < CHUNK; ++k) {
        const float xk = xv[k];
#pragma unroll
        for (int e = 0; e < EMAS; ++e) s[e] = fmaf(a[e], s[e], dec[e] * xk);
        f32x4 lo = {s[0], s[1], s[2], s[3]};
        f32x4 hi = {s[4], s[5], s[6], s[7]};
        op[0] = lo;
        op[1] = hi;
        op += opstride;
    }
}

// ---------------- Fallback: proven R6 halo kernel (67us) ----------------
// Used only if the harness workspace is smaller than 8 MiB.
#define HALO  128
#define U     16

__global__ __launch_bounds__(256) void ema_kernel(const float* __restrict__ x,
                                                  const float* __restrict__ log_decay,
                                                  float* __restrict__ out) {
    const int tid   = threadIdx.x;
    const int d     = tid & (DD - 1);
    const int bsub  = tid >> 7;
    const int bg    = blockIdx.x & 7;
    const int chunk = blockIdx.x >> 3;
    const int b     = bg * 2 + bsub;
    const int off   = b * DD + d;

    float dec[EMAS], a[EMAS];
    load_decays(log_decay, dec, a);

    const int cstart = chunk * CHUNK;
    int l0 = cstart - HALO;
    if (l0 < 0) l0 = 0;
    const int nsteps   = (cstart - l0) + CHUNK;
    const int nblk     = nsteps / U;
    const int halo_blk = (cstart - l0) / U;

    const float* xb = x + (size_t)l0 * BDSZ + off;

    const float s0 = *xb;
    float s[EMAS];
#pragma unroll
    for (int e = 0; e < EMAS; ++e) s[e] = s0;

    f32x4* op = (f32x4*)(out + ((size_t)cstart * BDSZ + off) * EMAS);
    const int opstride = BDSZ * EMAS / 4;

#define LOADBLK(BUF, IDX)                                                      \
    do {                                                                       \
        int _i = (IDX); if (_i > nblk - 1) _i = nblk - 1;                      \
        const float* _p = xb + (size_t)_i * U * BDSZ;                          \
        _Pragma("unroll")                                                      \
        for (int u = 0; u < U; ++u) (BUF)[u] = _p[(size_t)u * BDSZ];           \
    } while (0)

#define PROCESS(BUF, J)                                                        \
    do {                                                                       \
        if ((J) >= halo_blk) {                                                 \
            _Pragma("unroll")                                                  \
            for (int u = 0; u < U; ++u) {                                      \
                const float xv = (BUF)[u];                                     \
                _Pragma("unroll")                                              \
                for (int e = 0; e < EMAS; ++e)                                 \
                    s[e] = fmaf(a[e], s[e], dec[e] * xv);                      \
                f32x4 lo = {s[0], s[1], s[2], s[3]};                           \
                f32x4 hi = {s[4], s[5], s[6], s[7]};                           \
                op[0] = lo;                                                    \
                op[1] = hi;                                                    \
                op += opstride;                                                \
            }                                                                  \
        } else {                                                               \
            _Pragma("unroll")                                                  \
            for (int u = 0; u < U; ++u) {                                      \
                const float xv = (BUF)[u];                                     \
                _Pragma("unroll")                                              \
                for (int e = 0; e < EMAS; ++e)                                 \
                    s[e] = fmaf(a[e], s[e], dec[e] * xv);                      \
            }                                                                  \
        }                                                                      \
    } while (0)

    float b0[U], b1[U], b2[U];
    LOADBLK(b0, 0);
    LOADBLK(b1, 1);

    int j = 0;
    for (; j + 2 < nblk; j += 3) {
        LOADBLK(b2, j + 2);
        PROCESS(b0, j);
        LOADBLK(b0, j + 3);
        PROCESS(b1, j + 1);
        LOADBLK(b1, j + 4);
        PROCESS(b2, j + 2);
    }
    if (j < nblk)     PROCESS(b0, j);
    if (j + 1 < nblk) PROCESS(b1, j + 1);
#undef PROCESS
#undef LOADBLK
}

extern "C" void kernel_launch(void* const* d_in, const int* in_sizes, int n_in,
                              void* d_out, int out_size, void* d_ws, size_t ws_size,
                              hipStream_t stream) {
    const float* x  = (const float*)d_in[0];
    const float* ld = (const float*)d_in[1];
    float* out      = (float*)d_out;
    (void)in_sizes; (void)n_in; (void)out_size;

    if (d_ws && ws_size >= WS_BYTES) {
        float* hws = (float*)d_ws;
        ema_agg <<<dim3(NCHUNK * 8), dim3(256), 0, stream>>>(x, ld, hws);
        ema_scan<<<dim3(SLICE / 256), dim3(256), 0, stream>>>(x, ld, hws);
        ema_main<<<dim3(NCHUNK * 8), dim3(256), 0, stream>>>(x, ld, hws, out);
    } else {
        ema_kernel<<<dim3(NCHUNK * 8), dim3(256), 0, stream>>>(x, ld, out);
    }
}